// Round 1
// baseline (40.085 us; speedup 1.0000x reference)
//
#include <hip/hip_runtime.h>

// SphericalVectorPool: for each anchor R (out_coords), sum over sources r (coords):
//   E_k = exp(-mu_k * |r-R|),  wf = E_k * f
//   c0[k]   += wf                      (scaled by r_norms[k]*a_norm_0)
//   cv[c,k] += wf * (r-R)_c / |r-R|    (scaled by r_norms[k]*a_norm_1)
// Output layout [B, M, 64]: [c0(16), cvx(16), cvy(16), cvz(16)]

constexpr int NR    = 16;
constexpr int BATCH = 2;
constexpr int NSRC  = 2048;
constexpr int MOUT  = 2048;

__global__ __launch_bounds__(256) void svp_kernel(
    const float* __restrict__ f,       // [B,N]
    const float* __restrict__ coords,  // [B,N,3]
    const float* __restrict__ outc,    // [B,M,3]
    const float* __restrict__ mu,      // [16]
    const float* __restrict__ rn,      // [16]
    const float* __restrict__ an0,     // [1]
    const float* __restrict__ an1,     // [1]
    float* __restrict__ out)           // [B,M,64]
{
    const int wid  = (blockIdx.x * 256 + threadIdx.x) >> 6;  // one wave per anchor
    const int lane = threadIdx.x & 63;
    const int b = wid / MOUT;
    const int m = wid - b * MOUT;

    // per-k exponent constants: exp(-mu*d) = exp2(d * (-mu*log2e))
    const float LOG2E = 1.44269504088896340736f;
    float nmu[NR];
#pragma unroll
    for (int k = 0; k < NR; ++k) nmu[k] = -mu[k] * LOG2E;

    const float Rx = outc[(size_t)(b * MOUT + m) * 3 + 0];
    const float Ry = outc[(size_t)(b * MOUT + m) * 3 + 1];
    const float Rz = outc[(size_t)(b * MOUT + m) * 3 + 2];

    float a0[NR], ax[NR], ay[NR], az[NR];
#pragma unroll
    for (int k = 0; k < NR; ++k) { a0[k] = 0.f; ax[k] = 0.f; ay[k] = 0.f; az[k] = 0.f; }

    const float* cb = coords + (size_t)b * NSRC * 3;
    const float* fb = f + (size_t)b * NSRC;

    for (int n = lane; n < NSRC; n += 64) {
        const float cx = cb[n * 3 + 0];
        const float cy = cb[n * 3 + 1];
        const float cz = cb[n * 3 + 2];
        const float fv = fb[n];
        const float dx = cx - Rx, dy = cy - Ry, dz = cz - Rz;
        const float sq = dx * dx + dy * dy + dz * dz;
        const float rinv = __builtin_amdgcn_rsqf(sq);
        const float d  = sq * rinv;             // |r-R|
        const float ux = dx * rinv, uy = dy * rinv, uz = dz * rinv;
#pragma unroll
        for (int k = 0; k < NR; ++k) {
            const float e  = __builtin_amdgcn_exp2f(d * nmu[k]);
            const float wf = e * fv;
            a0[k] += wf;
            ax[k] += wf * ux;
            ay[k] += wf * uy;
            az[k] += wf * uz;
        }
    }

    // butterfly reduce each accumulator across the 64 lanes
#pragma unroll
    for (int k = 0; k < NR; ++k) {
#pragma unroll
        for (int mask = 1; mask < 64; mask <<= 1) {
            a0[k] += __shfl_xor(a0[k], mask, 64);
            ax[k] += __shfl_xor(ax[k], mask, 64);
            ay[k] += __shfl_xor(ay[k], mask, 64);
            az[k] += __shfl_xor(az[k], mask, 64);
        }
    }

    if (lane == 0) {
        float* o = out + (size_t)wid * 64;
        const float c0n = an0[0];
        const float c1n = an1[0];
#pragma unroll
        for (int k = 0; k < NR; ++k) {
            const float s0 = rn[k] * c0n;
            const float s1 = rn[k] * c1n;
            o[k]      = a0[k] * s0;
            o[16 + k] = ax[k] * s1;
            o[32 + k] = ay[k] * s1;
            o[48 + k] = az[k] * s1;
        }
    }
}

extern "C" void kernel_launch(void* const* d_in, const int* in_sizes, int n_in,
                              void* d_out, int out_size, void* d_ws, size_t ws_size,
                              hipStream_t stream) {
    const float* f      = (const float*)d_in[0];
    const float* coords = (const float*)d_in[1];
    const float* outc   = (const float*)d_in[2];
    const float* mu     = (const float*)d_in[3];
    const float* rn     = (const float*)d_in[4];
    const float* an0    = (const float*)d_in[5];
    const float* an1    = (const float*)d_in[6];
    float* out = (float*)d_out;

    const int anchors = BATCH * MOUT;          // 4096 waves
    dim3 grid(anchors / 4), block(256);        // 4 waves per block
    svp_kernel<<<grid, block, 0, stream>>>(f, coords, outc, mu, rn, an0, an1, out);
}

// Round 3
// 36.813 us; speedup vs baseline: 1.0889x; 1.0889x over previous
//
#include <hip/hip_runtime.h>

// SphericalVectorPool on MI355X.
// out[b,m,j] = scale(j) * sum_n exp(-mu[j&15]*|r_n-R_m|) * f_n * comp(j)
//   comp: j<16 -> 1 ; 16..31 -> ux ; 32..47 -> uy ; 48..63 -> uz
// Decomposition: 2 waves per anchor (each wave: 1024 sources, 64 register
// accumulators = the full 64-wide output row). Epilogue: bit-compaction
// transpose-reduce (63 shuffles) so lane j holds output j, cross-wave
// combine via LDS, coalesced 256B store per anchor.

constexpr int NR    = 16;
constexpr int BATCH = 2;
constexpr int NSRC  = 2048;
constexpr int MOUT  = 2048;

__global__ __launch_bounds__(256) void pack_kernel(
    const float* __restrict__ f,
    const float* __restrict__ coords,
    float4* __restrict__ packed)   // [B*N] of {x,y,z,f}
{
    int i = blockIdx.x * 256 + threadIdx.x;
    if (i < BATCH * NSRC) {
        packed[i] = make_float4(coords[i * 3 + 0], coords[i * 3 + 1],
                                coords[i * 3 + 2], f[i]);
    }
}

// transpose-reduce stage: after all 6 stages lane j holds sum over all 64
// lanes of original accumulator j. Each stage: keep the half of the live
// slots whose index-bit P matches this lane's bit P, add partner's copy.
#define STAGE(P, CNT)                                                     \
    {                                                                     \
        const bool mybit = (lane >> (P)) & 1;                             \
        _Pragma("unroll")                                                 \
        for (int t = 0; t < ((CNT) / 2); ++t) {                           \
            const float lo = v[2 * t], hi = v[2 * t + 1];                 \
            const float send = mybit ? lo : hi;                           \
            const float keep = mybit ? hi : lo;                           \
            v[t] = keep + __shfl_xor(send, 1 << (P), 64);                 \
        }                                                                 \
    }

__global__ __launch_bounds__(256) void svp_kernel(
    const float4* __restrict__ packed, // [B,N] {x,y,z,f}
    const float* __restrict__ outc,    // [B,M,3]
    const float* __restrict__ mu,      // [16]
    const float* __restrict__ rn,      // [16]
    const float* __restrict__ an0,     // [1]
    const float* __restrict__ an1,     // [1]
    float* __restrict__ out)           // [B,M,64]
{
    const int lane = threadIdx.x & 63;
    const int wib  = threadIdx.x >> 6;        // wave in block: 0..3
    const int aib  = wib >> 1;                // anchor in block: 0..1
    const int half = wib & 1;                 // which source half
    const int anchor = blockIdx.x * 2 + aib;  // 0..4095
    const int b = anchor >> 11;               // anchor / 2048

    __shared__ float red[2][64];

    // mu[] indexed with compile-time constants from a uniform pointer ->
    // scalar loads (SGPRs), no VGPR array.
    const float LOG2E = 1.44269504088896340736f;

    const float Rx = outc[(size_t)anchor * 3 + 0];
    const float Ry = outc[(size_t)anchor * 3 + 1];
    const float Rz = outc[(size_t)anchor * 3 + 2];

    float v[64];
#pragma unroll
    for (int j = 0; j < 64; ++j) v[j] = 0.f;

    const float4* pb = packed + (size_t)b * NSRC + half * (NSRC / 2);

#pragma unroll 2
    for (int i = 0; i < (NSRC / 2) / 64; ++i) {   // 16 iterations
        const float4 p = pb[i * 64 + lane];
        const float dx = p.x - Rx, dy = p.y - Ry, dz = p.z - Rz;
        const float fv = p.w;
        const float sq = dx * dx + dy * dy + dz * dz;
        const float rinv = __builtin_amdgcn_rsqf(sq);
        const float dd = (sq * rinv) * (-LOG2E);  // -log2e * |r-R|
        const float t  = fv * rinv;
        const float fx = t * dx, fy = t * dy, fz = t * dz;
#pragma unroll
        for (int k = 0; k < NR; ++k) {
            const float e = __builtin_amdgcn_exp2f(dd * mu[k]);
            v[k]      += e * fv;
            v[16 + k] += e * fx;
            v[32 + k] += e * fy;
            v[48 + k] += e * fz;
        }
    }

    STAGE(0, 64) STAGE(1, 32) STAGE(2, 16) STAGE(3, 8) STAGE(4, 4) STAGE(5, 2)
    const float r = v[0];   // lane j: output j, summed over this wave

    if (half == 1) red[aib][lane] = r;
    __syncthreads();
    if (half == 0) {
        const float tot = r + red[aib][lane];
        const float s = rn[lane & (NR - 1)] * (lane < NR ? an0[0] : an1[0]);
        out[(size_t)anchor * 64 + lane] = tot * s;
    }
}

extern "C" void kernel_launch(void* const* d_in, const int* in_sizes, int n_in,
                              void* d_out, int out_size, void* d_ws, size_t ws_size,
                              hipStream_t stream) {
    const float* f      = (const float*)d_in[0];
    const float* coords = (const float*)d_in[1];
    const float* outc   = (const float*)d_in[2];
    const float* mu     = (const float*)d_in[3];
    const float* rn     = (const float*)d_in[4];
    const float* an0    = (const float*)d_in[5];
    const float* an1    = (const float*)d_in[6];
    float* out = (float*)d_out;
    float4* packed = (float4*)d_ws;   // B*N*16B = 64 KiB

    pack_kernel<<<(BATCH * NSRC + 255) / 256, 256, 0, stream>>>(f, coords, packed);

    const int anchors = BATCH * MOUT;              // 4096
    svp_kernel<<<anchors / 2, 256, 0, stream>>>(packed, outc, mu, rn, an0, an1, out);
}

// Round 7
// 36.419 us; speedup vs baseline: 1.1007x; 1.0108x over previous
//
#include <hip/hip_runtime.h>

// SphericalVectorPool on MI355X — packed-FP32 via compiler-selected v_pk_fma_f32.
// out[b,m,j] = scale(j) * sum_n exp(-mu[j&15]*|r_n-R_m|) * f_n * comp(j)
//   comp: j<16 -> 1 ; 16..31 -> ux ; 32..47 -> uy ; 48..63 -> uz
// 2 waves per anchor; 64 accumulators held as v2f[8] x 4 components updated
// with __builtin_elementwise_fma on ext_vector floats (LLVM selects
// v_pk_fma_f32 on gfx950; falls back to scalar FMA with identical math).
// Epilogue: bit-compaction transpose-reduce so lane j holds output j,
// coalesced 256B store per anchor.

constexpr int NR    = 16;
constexpr int BATCH = 2;
constexpr int NSRC  = 2048;
constexpr int MOUT  = 2048;

typedef float v2f __attribute__((ext_vector_type(2)));

__global__ __launch_bounds__(256) void pack_kernel(
    const float* __restrict__ f,
    const float* __restrict__ coords,
    float4* __restrict__ packed)   // [B*N] of {x,y,z,f}
{
    int i = blockIdx.x * 256 + threadIdx.x;
    if (i < BATCH * NSRC) {
        packed[i] = make_float4(coords[i * 3 + 0], coords[i * 3 + 1],
                                coords[i * 3 + 2], f[i]);
    }
}

#define STAGE(P, CNT)                                                     \
    {                                                                     \
        const bool mybit = (lane >> (P)) & 1;                             \
        _Pragma("unroll")                                                 \
        for (int t = 0; t < ((CNT) / 2); ++t) {                           \
            const float lo = v[2 * t], hi = v[2 * t + 1];                 \
            const float send = mybit ? lo : hi;                           \
            const float keep = mybit ? hi : lo;                           \
            v[t] = keep + __shfl_xor(send, 1 << (P), 64);                 \
        }                                                                 \
    }

__global__ __launch_bounds__(256) void svp_kernel(
    const float4* __restrict__ packed, // [B,N] {x,y,z,f}
    const float* __restrict__ outc,    // [B,M,3]
    const float* __restrict__ mu,      // [16]
    const float* __restrict__ rn,      // [16]
    const float* __restrict__ an0,     // [1]
    const float* __restrict__ an1,     // [1]
    float* __restrict__ out)           // [B,M,64]
{
    const int lane = threadIdx.x & 63;
    const int wib  = threadIdx.x >> 6;        // wave in block: 0..3
    const int aib  = wib >> 1;                // anchor in block: 0..1
    const int half = wib & 1;                 // which source half
    const int anchor = blockIdx.x * 2 + aib;  // 0..4095
    const int b = anchor >> 11;

    __shared__ float red[2][64];

    const float LOG2E = 1.44269504088896340736f;

    const float Rx = outc[(size_t)anchor * 3 + 0];
    const float Ry = outc[(size_t)anchor * 3 + 1];
    const float Rz = outc[(size_t)anchor * 3 + 2];

    v2f v0[8], vx[8], vy[8], vz[8];
#pragma unroll
    for (int t = 0; t < 8; ++t) {
        v0[t] = (v2f)(0.f); vx[t] = (v2f)(0.f);
        vy[t] = (v2f)(0.f); vz[t] = (v2f)(0.f);
    }

    const float4* pb = packed + (size_t)b * NSRC + half * (NSRC / 2);

#pragma unroll 2
    for (int i = 0; i < (NSRC / 2) / 64; ++i) {   // 16 iterations
        const float4 p = pb[i * 64 + lane];
        const float dx = p.x - Rx, dy = p.y - Ry, dz = p.z - Rz;
        const float fv = p.w;
        const float sq = dx * dx + dy * dy + dz * dz;
        const float rinv = __builtin_amdgcn_rsqf(sq);
        const float dd = (sq * rinv) * (-LOG2E);  // -log2e * |r-R|
        const float t  = fv * rinv;
        const float fx = t * dx, fy = t * dy, fz = t * dz;
        const v2f fv2 = {fv, fv};
        const v2f fx2 = {fx, fx};
        const v2f fy2 = {fy, fy};
        const v2f fz2 = {fz, fz};
#pragma unroll
        for (int t8 = 0; t8 < 8; ++t8) {
            const float e0 = __builtin_amdgcn_exp2f(dd * mu[2 * t8]);
            const float e1 = __builtin_amdgcn_exp2f(dd * mu[2 * t8 + 1]);
            const v2f e2 = {e0, e1};
            v0[t8] = __builtin_elementwise_fma(e2, fv2, v0[t8]);
            vx[t8] = __builtin_elementwise_fma(e2, fx2, vx[t8]);
            vy[t8] = __builtin_elementwise_fma(e2, fy2, vy[t8]);
            vz[t8] = __builtin_elementwise_fma(e2, fz2, vz[t8]);
        }
    }

    // unpack to 64 scalars (register renaming only)
    float v[64];
#pragma unroll
    for (int t = 0; t < 8; ++t) {
        v[2 * t]          = v0[t][0]; v[2 * t + 1]      = v0[t][1];
        v[16 + 2 * t]     = vx[t][0]; v[16 + 2 * t + 1] = vx[t][1];
        v[32 + 2 * t]     = vy[t][0]; v[32 + 2 * t + 1] = vy[t][1];
        v[48 + 2 * t]     = vz[t][0]; v[48 + 2 * t + 1] = vz[t][1];
    }

    STAGE(0, 64) STAGE(1, 32) STAGE(2, 16) STAGE(3, 8) STAGE(4, 4) STAGE(5, 2)
    const float r = v[0];   // lane j: output j, summed over this wave

    if (half == 1) red[aib][lane] = r;
    __syncthreads();
    if (half == 0) {
        const float tot = r + red[aib][lane];
        const float s = rn[lane & (NR - 1)] * (lane < NR ? an0[0] : an1[0]);
        out[(size_t)anchor * 64 + lane] = tot * s;
    }
}

extern "C" void kernel_launch(void* const* d_in, const int* in_sizes, int n_in,
                              void* d_out, int out_size, void* d_ws, size_t ws_size,
                              hipStream_t stream) {
    const float* f      = (const float*)d_in[0];
    const float* coords = (const float*)d_in[1];
    const float* outc   = (const float*)d_in[2];
    const float* mu     = (const float*)d_in[3];
    const float* rn     = (const float*)d_in[4];
    const float* an0    = (const float*)d_in[5];
    const float* an1    = (const float*)d_in[6];
    float* out = (float*)d_out;
    float4* packed = (float4*)d_ws;   // B*N*16B = 64 KiB

    pack_kernel<<<(BATCH * NSRC + 255) / 256, 256, 0, stream>>>(f, coords, packed);

    const int anchors = BATCH * MOUT;              // 4096
    svp_kernel<<<anchors / 2, 256, 0, stream>>>(packed, outc, mu, rn, an0, an1, out);
}

// Round 8
// 36.268 us; speedup vs baseline: 1.1053x; 1.0042x over previous
//
#include <hip/hip_runtime.h>

// SphericalVectorPool on MI355X.
// out[b,m,j] = scale(j) * sum_n exp(-mu[j&15]*|r_n-R_m|) * f_n * comp(j)
//   comp: j<16 -> 1 ; 16..31 -> ux ; 32..47 -> uy ; 48..63 -> uz
// 2 waves per anchor; 64 fp32 accumulators as v2f[8] x 4 components
// (v_pk_fma_f32). mu pre-hoisted to registers premultiplied by -log2e
// (packed pairs -> v_pk_mul forms both exp args at once). Explicit depth-2
// prefetch on the packed float4 source stream. Epilogue: bit-compaction
// transpose-reduce so lane j holds output j, coalesced 256B store.

constexpr int NR    = 16;
constexpr int BATCH = 2;
constexpr int NSRC  = 2048;
constexpr int MOUT  = 2048;

typedef float v2f __attribute__((ext_vector_type(2)));

__global__ __launch_bounds__(256) void pack_kernel(
    const float* __restrict__ f,
    const float* __restrict__ coords,
    float4* __restrict__ packed)   // [B*N] of {x,y,z,f}
{
    int i = blockIdx.x * 256 + threadIdx.x;
    if (i < BATCH * NSRC) {
        packed[i] = make_float4(coords[i * 3 + 0], coords[i * 3 + 1],
                                coords[i * 3 + 2], f[i]);
    }
}

#define STAGE(P, CNT)                                                     \
    {                                                                     \
        const bool mybit = (lane >> (P)) & 1;                             \
        _Pragma("unroll")                                                 \
        for (int t = 0; t < ((CNT) / 2); ++t) {                           \
            const float lo = v[2 * t], hi = v[2 * t + 1];                 \
            const float send = mybit ? lo : hi;                           \
            const float keep = mybit ? hi : lo;                           \
            v[t] = keep + __shfl_xor(send, 1 << (P), 64);                 \
        }                                                                 \
    }

__global__ __launch_bounds__(256) void svp_kernel(
    const float4* __restrict__ packed, // [B,N] {x,y,z,f}
    const float* __restrict__ outc,    // [B,M,3]
    const float* __restrict__ mu,      // [16]
    const float* __restrict__ rn,      // [16]
    const float* __restrict__ an0,     // [1]
    const float* __restrict__ an1,     // [1]
    float* __restrict__ out)           // [B,M,64]
{
    const int lane = threadIdx.x & 63;
    const int wib  = threadIdx.x >> 6;        // wave in block: 0..3
    const int aib  = wib >> 1;                // anchor in block: 0..1
    const int half = wib & 1;                 // which source half
    const int anchor = blockIdx.x * 2 + aib;  // 0..4095
    const int b = anchor >> 11;

    __shared__ float red[2][64];

    // Hoist mu into registers, premultiplied by -log2e, as packed pairs.
    const float NL2E = -1.44269504088896340736f;
    v2f nmu[8];
#pragma unroll
    for (int t = 0; t < 8; ++t) {
        nmu[t] = (v2f){mu[2 * t] * NL2E, mu[2 * t + 1] * NL2E};
    }

    const float Rx = outc[(size_t)anchor * 3 + 0];
    const float Ry = outc[(size_t)anchor * 3 + 1];
    const float Rz = outc[(size_t)anchor * 3 + 2];

    v2f v0[8], vx[8], vy[8], vz[8];
#pragma unroll
    for (int t = 0; t < 8; ++t) {
        v0[t] = (v2f)(0.f); vx[t] = (v2f)(0.f);
        vy[t] = (v2f)(0.f); vz[t] = (v2f)(0.f);
    }

    const float4* pb = packed + (size_t)b * NSRC + half * (NSRC / 2);

    // depth-2 software prefetch on the source stream
    float4 p = pb[lane];
#pragma unroll 2
    for (int i = 0; i < (NSRC / 2) / 64; ++i) {   // 16 iterations
        const int nx = (i < 15) ? (i + 1) : 15;   // branchless clamp
        const float4 pn = pb[nx * 64 + lane];     // prefetch next tile

        const float dx = p.x - Rx, dy = p.y - Ry, dz = p.z - Rz;
        const float fv = p.w;
        const float sq = dx * dx + dy * dy + dz * dz;
        const float rinv = __builtin_amdgcn_rsqf(sq);
        const float d  = sq * rinv;               // |r-R|
        const float t  = fv * rinv;
        const float fx = t * dx, fy = t * dy, fz = t * dz;
        const v2f d2  = {d, d};
        const v2f fv2 = {fv, fv};
        const v2f fx2 = {fx, fx};
        const v2f fy2 = {fy, fy};
        const v2f fz2 = {fz, fz};
#pragma unroll
        for (int t8 = 0; t8 < 8; ++t8) {
            const v2f arg = d2 * nmu[t8];         // v_pk_mul_f32
            const v2f e2  = {__builtin_amdgcn_exp2f(arg.x),
                             __builtin_amdgcn_exp2f(arg.y)};
            v0[t8] = __builtin_elementwise_fma(e2, fv2, v0[t8]);
            vx[t8] = __builtin_elementwise_fma(e2, fx2, vx[t8]);
            vy[t8] = __builtin_elementwise_fma(e2, fy2, vy[t8]);
            vz[t8] = __builtin_elementwise_fma(e2, fz2, vz[t8]);
        }
        p = pn;
    }

    // unpack to 64 scalars (register renaming only)
    float v[64];
#pragma unroll
    for (int t = 0; t < 8; ++t) {
        v[2 * t]          = v0[t][0]; v[2 * t + 1]      = v0[t][1];
        v[16 + 2 * t]     = vx[t][0]; v[16 + 2 * t + 1] = vx[t][1];
        v[32 + 2 * t]     = vy[t][0]; v[32 + 2 * t + 1] = vy[t][1];
        v[48 + 2 * t]     = vz[t][0]; v[48 + 2 * t + 1] = vz[t][1];
    }

    STAGE(0, 64) STAGE(1, 32) STAGE(2, 16) STAGE(3, 8) STAGE(4, 4) STAGE(5, 2)
    const float r = v[0];   // lane j: output j, summed over this wave

    if (half == 1) red[aib][lane] = r;
    __syncthreads();
    if (half == 0) {
        const float tot = r + red[aib][lane];
        const float s = rn[lane & (NR - 1)] * (lane < NR ? an0[0] : an1[0]);
        out[(size_t)anchor * 64 + lane] = tot * s;
    }
}

extern "C" void kernel_launch(void* const* d_in, const int* in_sizes, int n_in,
                              void* d_out, int out_size, void* d_ws, size_t ws_size,
                              hipStream_t stream) {
    const float* f      = (const float*)d_in[0];
    const float* coords = (const float*)d_in[1];
    const float* outc   = (const float*)d_in[2];
    const float* mu     = (const float*)d_in[3];
    const float* rn     = (const float*)d_in[4];
    const float* an0    = (const float*)d_in[5];
    const float* an1    = (const float*)d_in[6];
    float* out = (float*)d_out;
    float4* packed = (float4*)d_ws;   // B*N*16B = 64 KiB

    pack_kernel<<<(BATCH * NSRC + 255) / 256, 256, 0, stream>>>(f, coords, packed);

    const int anchors = BATCH * MOUT;              // 4096
    svp_kernel<<<anchors / 2, 256, 0, stream>>>(packed, outc, mu, rn, an0, an1, out);
}